// Round 3
// baseline (299.664 us; speedup 1.0000x reference)
//
#include <hip/hip_runtime.h>
#include <stdint.h>

#define NROWS 8192
#define DDIM  128
#define PPART 16
#define JT_PER_PART ((NROWS/16)/PPART)   // 32 column tiles per partition
#define WPB   4                          // waves per block
#define LOG2E_X100 144.26950408889634f   // 100 / ln(2)
#define LN2F       0.6931471805599453f

typedef __bf16 bf16x8 __attribute__((ext_vector_type(8)));
typedef float  f32x4  __attribute__((ext_vector_type(4)));

__device__ __forceinline__ unsigned short f2bf_rne(float f) {
    union { float f; uint32_t u; } v; v.f = f;
    uint32_t r = (v.u + 0x7FFFu + ((v.u >> 16) & 1u)) >> 16;
    return (unsigned short)r;
}

// Kernel 1: fp32 -> bf16. ts pre-scaled by 100*log2(e) (base-2 softmax space).
__global__ void convert_kernel(const float* __restrict__ ts, const float* __restrict__ nt,
                               unsigned short* __restrict__ ts_bf,
                               unsigned short* __restrict__ nt_bf,
                               float* __restrict__ acc, int* __restrict__ ticket) {
    const int nvec = (NROWS * DDIM) / 4;
    int tid = blockIdx.x * blockDim.x + threadIdx.x;
    bool isNT = tid >= nvec;
    int i = isNT ? (tid - nvec) : tid;
    const float4 v = ((const float4*)(isNT ? nt : ts))[i];
    float sc = isNT ? 1.0f : LOG2E_X100;
    ushort4 o;
    o.x = f2bf_rne(v.x * sc); o.y = f2bf_rne(v.y * sc);
    o.z = f2bf_rne(v.z * sc); o.w = f2bf_rne(v.w * sc);
    ((ushort4*)(isNT ? nt_bf : ts_bf))[i] = o;
    if (tid == 0) { *acc = 0.0f; *ticket = 0; }
}

// Kernel 2: per-row online-softmax stats, base-2 space.
// 4 waves/block; each wave owns ONE 16-row strip, walks j-tiles in PAIRS.
// All 4 waves of a block share (part,dir) => same B tiles => L1 reuse.
// Slim register footprint (~83 VGPR incl. acc) => 6 waves/SIMD.
// grid = (NROWS/16/WPB, PPART, 2)
__global__ __launch_bounds__(256, 6) void rowstats_kernel(
        const unsigned short* __restrict__ ts_bf,
        const unsigned short* __restrict__ nt_bf,
        float* __restrict__ pm, float* __restrict__ ps, float* __restrict__ pd) {
    const int lane = threadIdx.x & 63;
    const int wv   = threadIdx.x >> 6;
    const int c    = lane & 15;
    const int quad = lane >> 4;
    const int grp  = blockIdx.x * WPB + wv;     // 16-row strip id, 0..511
    const int rows0 = grp * 16;
    const int part = blockIdx.y;
    const int dir  = blockIdx.z;

    const unsigned short* A = dir ? nt_bf : ts_bf;
    const unsigned short* B = dir ? ts_bf : nt_bf;

    bf16x8 a[4];
    {
        const unsigned short* abase = A + (rows0 + c) * DDIM + quad * 8;
#pragma unroll
        for (int kc = 0; kc < 4; ++kc) a[kc] = *(const bf16x8*)(abase + kc * 32);
    }

    float m[4], ss[4], dg[4];
#pragma unroll
    for (int r = 0; r < 4; ++r) { m[r] = -INFINITY; ss[r] = 0.0f; dg[r] = 0.0f; }

    // pair index (within this partition's 16 pairs) containing this strip's diag tile
    const int diag_t    = (grp >> 1) - part * (JT_PER_PART / 2);
    const int diag_slot = grp & 1;              // 0 => even slot (A), 1 => odd slot (B)

    const unsigned short* bptr = B + (part * JT_PER_PART * 16 + c) * DDIM + quad * 8;

    for (int t = 0; t < JT_PER_PART / 2; ++t) {
        bf16x8 bA[4], bB[4];
#pragma unroll
        for (int kc = 0; kc < 4; ++kc) {
            bA[kc] = *(const bf16x8*)(bptr + kc * 32);
            bB[kc] = *(const bf16x8*)(bptr + 16 * DDIM + kc * 32);
        }
        bptr += 32 * DDIM;

        f32x4 accA = {0,0,0,0}, accB = {0,0,0,0};
#pragma unroll
        for (int kc = 0; kc < 4; ++kc) {
            accA = __builtin_amdgcn_mfma_f32_16x16x32_bf16(a[kc], bA[kc], accA, 0, 0, 0);
            accB = __builtin_amdgcn_mfma_f32_16x16x32_bf16(a[kc], bB[kc], accB, 0, 0, 0);
        }

        const bool pd_ = (t == diag_t);         // wave-uniform
#pragma unroll
        for (int r = 0; r < 4; ++r) {
            float xA = accA[r], xB = accB[r];
            if (pd_) {
                bool onDiag = (c == quad * 4 + r);
                if (diag_slot == 0) { if (onDiag) dg[r] += xA; xA = onDiag ? xA : -1.0e30f; }
                else                { if (onDiag) dg[r] += xB; xB = onDiag ? xB : -1.0e30f; }
            }
            float mn = fmaxf(fmaxf(m[r], xA), xB);   // -> v_max3_f32
            ss[r] = ss[r] * __builtin_amdgcn_exp2f(m[r] - mn)
                  + __builtin_amdgcn_exp2f(xA - mn)
                  + __builtin_amdgcn_exp2f(xB - mn);
            m[r] = mn;
        }
    }

    // Combine across the 16 lanes of each quad (they share the same 4 rows).
#pragma unroll
    for (int r = 0; r < 4; ++r) {
        float mm = m[r], sv = ss[r], dd = dg[r];
#pragma unroll
        for (int off = 1; off < 16; off <<= 1) {
            float m2 = __shfl_xor(mm, off, 64);
            float s2 = __shfl_xor(sv, off, 64);
            float d2 = __shfl_xor(dd, off, 64);
            float mn = fmaxf(mm, m2);
            sv = sv * __builtin_amdgcn_exp2f(mm - mn) + s2 * __builtin_amdgcn_exp2f(m2 - mn);
            mm = mn;
            dd += d2;
        }
        if (c == 0) {
            int row = rows0 + quad * 4 + r;
            int idx = (dir * NROWS + row) * PPART + part;
            pm[idx] = mm; ps[idx] = sv; pd[idx] = dd;
        }
    }
}

// Kernel 3: merge partitions per (dir,row), block-reduce, atomicAdd;
// last block finalizes the scalar output (base-2 -> natural via ln2).
__global__ void merge_kernel(const float* __restrict__ pm, const float* __restrict__ ps,
                             const float* __restrict__ pd, float* __restrict__ acc,
                             int* __restrict__ ticket, float* __restrict__ out) {
    int tid = blockIdx.x * blockDim.x + threadIdx.x;  // 0 .. 2*NROWS-1
    const float* pmr = pm + tid * PPART;
    const float* psr = ps + tid * PPART;
    const float* pdr = pd + tid * PPART;
    float mt = -INFINITY;
#pragma unroll
    for (int p = 0; p < PPART; ++p) mt = fmaxf(mt, pmr[p]);
    float st = 0.0f, dt = 0.0f;
#pragma unroll
    for (int p = 0; p < PPART; ++p) {
        st += psr[p] * __builtin_amdgcn_exp2f(pmr[p] - mt);
        dt += pdr[p];
    }
    float lsm = dt - mt - __builtin_amdgcn_logf(st);   // base-2 log-softmax at diagonal

    float v = lsm;
#pragma unroll
    for (int off = 32; off; off >>= 1) v += __shfl_down(v, off, 64);
    __shared__ float wsum[4];
    if ((threadIdx.x & 63) == 0) wsum[threadIdx.x >> 6] = v;
    __syncthreads();
    if (threadIdx.x == 0) {
        atomicAdd(acc, wsum[0] + wsum[1] + wsum[2] + wsum[3]);
        __threadfence();
        int old = atomicAdd(ticket, 1);
        if (old == (int)gridDim.x - 1) {
            __threadfence();
            float tot = atomicAdd(acc, 0.0f);   // coherent read of final sum
            float t = -(tot * LN2F) / (2.0f * NROWS);
            if (!isfinite(t)) t = 0.0f;
            out[0] = t;
        }
    }
}

extern "C" void kernel_launch(void* const* d_in, const int* in_sizes, int n_in,
                              void* d_out, int out_size, void* d_ws, size_t ws_size,
                              hipStream_t stream) {
    const float* ts = (const float*)d_in[0];
    const float* nt = (const float*)d_in[1];
    float* out = (float*)d_out;

    unsigned short* ts_bf = (unsigned short*)d_ws;                 // 2 MB
    unsigned short* nt_bf = ts_bf + NROWS * DDIM;                  // 2 MB
    float* pm = (float*)(nt_bf + NROWS * DDIM);                    // 1 MB
    float* ps = pm + 2 * NROWS * PPART;                            // 1 MB
    float* pd = ps + 2 * NROWS * PPART;                            // 1 MB
    float* acc = pd + 2 * NROWS * PPART;                           // 4 B
    int* ticket = (int*)(acc + 1);                                 // 4 B

    convert_kernel<<<2048, 256, 0, stream>>>(ts, nt, ts_bf, nt_bf, acc, ticket);
    rowstats_kernel<<<dim3(NROWS / 16 / WPB, PPART, 2), 256, 0, stream>>>(ts_bf, nt_bf, pm, ps, pd);
    merge_kernel<<<(2 * NROWS) / 256, 256, 0, stream>>>(pm, ps, pd, acc, ticket, out);
}

// Round 4
// 117.491 us; speedup vs baseline: 2.5505x; 2.5505x over previous
//
#include <hip/hip_runtime.h>
#include <stdint.h>

#define NROWS 8192
#define DDIM  128
#define PPART 8
#define BROWS 256                        // rows per block = 8 waves * 32
#define NITER 32                         // (NROWS/PPART)/32 j-pairs per partition
#define LOG2E_X100 144.26950408889634f   // 100 / ln(2)
#define LN2F       0.6931471805599453f

typedef __bf16 bf16x8 __attribute__((ext_vector_type(8)));
typedef float  f32x4  __attribute__((ext_vector_type(4)));

__device__ __forceinline__ unsigned short f2bf_rne(float f) {
    union { float f; uint32_t u; } v; v.f = f;
    uint32_t r = (v.u + 0x7FFFu + ((v.u >> 16) & 1u)) >> 16;
    return (unsigned short)r;
}

// async global->LDS, 16B per lane; lds dest = (uniform base) + lane*16
__device__ __forceinline__ void async16(const unsigned short* g, unsigned char* l) {
    __builtin_amdgcn_global_load_lds(
        (const __attribute__((address_space(1))) unsigned int*)g,
        (__attribute__((address_space(3))) unsigned int*)l, 16, 0, 0);
}

// Kernel 1: fp32 -> bf16. ts pre-scaled by 100*log2(e) (base-2 softmax space).
__global__ void convert_kernel(const float* __restrict__ ts, const float* __restrict__ nt,
                               unsigned short* __restrict__ ts_bf,
                               unsigned short* __restrict__ nt_bf,
                               float* __restrict__ acc, int* __restrict__ ticket) {
    const int nvec = (NROWS * DDIM) / 4;
    int tid = blockIdx.x * blockDim.x + threadIdx.x;
    bool isNT = tid >= nvec;
    int i = isNT ? (tid - nvec) : tid;
    const float4 v = ((const float4*)(isNT ? nt : ts))[i];
    float sc = isNT ? 1.0f : LOG2E_X100;
    ushort4 o;
    o.x = f2bf_rne(v.x * sc); o.y = f2bf_rne(v.y * sc);
    o.z = f2bf_rne(v.z * sc); o.w = f2bf_rne(v.w * sc);
    ((ushort4*)(isNT ? nt_bf : ts_bf))[i] = o;
    if (tid == 0) { *acc = 0.0f; *ticket = 0; }
}

// DMA one j-PAIR tile (32 rows x 128 cols bf16 = 8 KB) into LDS, xor-swizzled:
// chunk ch (16B) of row r is placed at row-local position ch ^ (r&7).
// Executed by wave 0 only. 8 instructions, 1 KB each.
__device__ __forceinline__ void dma_pair(const unsigned short* gbase, unsigned char* lds, int lane) {
#pragma unroll
    for (int u = 0; u < 8; ++u) {
        int r  = u * 4 + (lane >> 4);          // pair row 0..31
        int ch = (lane & 15) ^ (r & 7);        // which global 16B chunk this lane fetches
        async16(gbase + r * 128 + ch * 8, lds + u * 1024);
    }
}

// Kernel 2: per-row online-softmax stats, base-2 space.
// 8 waves/block (512 thr); each wave = 32 rows (2 strips). All waves share the
// block's B-walk staged in double-buffered LDS (xor-swizzled, conflict-free
// ds_read_b128). grid = (NROWS/BROWS, PPART, 2).
__global__ __launch_bounds__(512, 4) void rowstats_kernel(
        const unsigned short* __restrict__ ts_bf,
        const unsigned short* __restrict__ nt_bf,
        float* __restrict__ pm, float* __restrict__ ps, float* __restrict__ pd) {
    __shared__ unsigned char smem[2 * 8192];

    const int lane = threadIdx.x & 63;
    const int wv   = threadIdx.x >> 6;         // 0..7
    const int c    = lane & 15;
    const int quad = lane >> 4;
    const int bx   = blockIdx.x;               // 0..31
    const int part = blockIdx.y;               // 0..7
    const int dir  = blockIdx.z;
    const int rows0 = bx * BROWS + wv * 32;

    const unsigned short* A = dir ? nt_bf : ts_bf;
    const unsigned short* B = dir ? ts_bf : nt_bf;

    // A fragments: this wave's 32 rows, held in regs (32 VGPRs).
    bf16x8 a[2][4];
#pragma unroll
    for (int s = 0; s < 2; ++s) {
        const unsigned short* abase = A + (rows0 + s * 16 + c) * DDIM + quad * 8;
#pragma unroll
        for (int kc = 0; kc < 4; ++kc)
            a[s][kc] = *(const bf16x8*)(abase + kc * 32);
    }

    float m[2][4], ss[2][4], dg[2][4];
#pragma unroll
    for (int s = 0; s < 2; ++s)
#pragma unroll
        for (int r = 0; r < 4; ++r) { m[r? (r):(r)][0] = m[s][r]; } // (no-op to keep arrays together)
#pragma unroll
    for (int s = 0; s < 2; ++s)
#pragma unroll
        for (int r = 0; r < 4; ++r) { m[s][r] = -INFINITY; ss[s][r] = 0.0f; dg[s][r] = 0.0f; }

    // Diagonal: this block's rows live in partition bx>>2; this wave's diag pair
    // index is (bx&3)*8 + wv. Strip 0's diag tile is slot A, strip 1's slot B.
    const bool havePart = (part == (bx >> 2));
    const int  diag_t   = ((bx & 3) << 3) + wv;

    const unsigned short* bwalk = B + (part * (NROWS / PPART)) * DDIM;  // partition col base

    if (wv == 0) dma_pair(bwalk, smem, lane);
    __syncthreads();

    const int ldsoff0 = c * 256 + (((0 * 4) + quad) ^ (c & 7)) * 16;   // kc=0 strip0 (pattern; others inline)

    for (int t = 0; t < NITER; ++t) {
        if (wv == 0 && t + 1 < NITER)
            dma_pair(bwalk + (t + 1) * 32 * DDIM, smem + ((t + 1) & 1) * 8192, lane);

        const unsigned char* buf = smem + (t & 1) * 8192;

        f32x4 aA0 = {0,0,0,0}, aA1 = {0,0,0,0}, aB0 = {0,0,0,0}, aB1 = {0,0,0,0};
#pragma unroll
        for (int kc = 0; kc < 4; ++kc) {
            const int sw = ((kc * 4 + quad) ^ (c & 7)) * 16;
            bf16x8 bA = *(const bf16x8*)(buf + c * 256 + sw);
            bf16x8 bB = *(const bf16x8*)(buf + (16 + c) * 256 + sw);
            aA0 = __builtin_amdgcn_mfma_f32_16x16x32_bf16(a[0][kc], bA, aA0, 0, 0, 0);
            aA1 = __builtin_amdgcn_mfma_f32_16x16x32_bf16(a[1][kc], bA, aA1, 0, 0, 0);
            aB0 = __builtin_amdgcn_mfma_f32_16x16x32_bf16(a[0][kc], bB, aB0, 0, 0, 0);
            aB1 = __builtin_amdgcn_mfma_f32_16x16x32_bf16(a[1][kc], bB, aB1, 0, 0, 0);
        }

        const bool pd_ = havePart && (t == diag_t);   // wave-uniform
#pragma unroll
        for (int s = 0; s < 2; ++s) {
#pragma unroll
            for (int r = 0; r < 4; ++r) {
                float xA = s ? aA1[r] : aA0[r];
                float xB = s ? aB1[r] : aB0[r];
                if (pd_) {
                    bool onDiag = (c == quad * 4 + r);
                    if (s == 0) { if (onDiag) dg[0][r] += xA; xA = onDiag ? xA : -1.0e30f; }
                    else        { if (onDiag) dg[1][r] += xB; xB = onDiag ? xB : -1.0e30f; }
                }
                float mn = fmaxf(fmaxf(m[s][r], xA), xB);    // v_max3_f32
                ss[s][r] = ss[s][r] * __builtin_amdgcn_exp2f(m[s][r] - mn)
                         + __builtin_amdgcn_exp2f(xA - mn)
                         + __builtin_amdgcn_exp2f(xB - mn);
                m[s][r] = mn;
            }
        }
        __syncthreads();
    }

    // Combine across the 16 lanes of each quad (they share the same 4 rows).
#pragma unroll
    for (int s = 0; s < 2; ++s) {
#pragma unroll
        for (int r = 0; r < 4; ++r) {
            float mm = m[s][r], sv = ss[s][r], dd = dg[s][r];
#pragma unroll
            for (int off = 1; off < 16; off <<= 1) {
                float m2 = __shfl_xor(mm, off, 64);
                float s2 = __shfl_xor(sv, off, 64);
                float d2 = __shfl_xor(dd, off, 64);
                float mn = fmaxf(mm, m2);
                sv = sv * __builtin_amdgcn_exp2f(mm - mn) + s2 * __builtin_amdgcn_exp2f(m2 - mn);
                mm = mn;
                dd += d2;
            }
            if (c == 0) {
                int row = rows0 + s * 16 + quad * 4 + r;
                int idx = (dir * NROWS + row) * PPART + part;
                pm[idx] = mm; ps[idx] = sv; pd[idx] = dd;
            }
        }
    }
}

// Kernel 3: merge partitions per (dir,row), block-reduce, atomicAdd;
// last block finalizes the scalar output (base-2 -> natural via ln2).
__global__ void merge_kernel(const float* __restrict__ pm, const float* __restrict__ ps,
                             const float* __restrict__ pd, float* __restrict__ acc,
                             int* __restrict__ ticket, float* __restrict__ out) {
    int tid = blockIdx.x * blockDim.x + threadIdx.x;  // 0 .. 2*NROWS-1
    const float* pmr = pm + tid * PPART;
    const float* psr = ps + tid * PPART;
    const float* pdr = pd + tid * PPART;
    float mt = -INFINITY;
#pragma unroll
    for (int p = 0; p < PPART; ++p) mt = fmaxf(mt, pmr[p]);
    float st = 0.0f, dt = 0.0f;
#pragma unroll
    for (int p = 0; p < PPART; ++p) {
        st += psr[p] * __builtin_amdgcn_exp2f(pmr[p] - mt);
        dt += pdr[p];
    }
    float lsm = dt - mt - __builtin_amdgcn_logf(st);   // base-2 log-softmax at diagonal

    float v = lsm;
#pragma unroll
    for (int off = 32; off; off >>= 1) v += __shfl_down(v, off, 64);
    __shared__ float wsum[4];
    if ((threadIdx.x & 63) == 0) wsum[threadIdx.x >> 6] = v;
    __syncthreads();
    if (threadIdx.x == 0) {
        atomicAdd(acc, wsum[0] + wsum[1] + wsum[2] + wsum[3]);
        __threadfence();
        int old = atomicAdd(ticket, 1);
        if (old == (int)gridDim.x - 1) {
            __threadfence();
            float tot = atomicAdd(acc, 0.0f);   // coherent read of final sum
            float t = -(tot * LN2F) / (2.0f * NROWS);
            if (!isfinite(t)) t = 0.0f;
            out[0] = t;
        }
    }
}

extern "C" void kernel_launch(void* const* d_in, const int* in_sizes, int n_in,
                              void* d_out, int out_size, void* d_ws, size_t ws_size,
                              hipStream_t stream) {
    const float* ts = (const float*)d_in[0];
    const float* nt = (const float*)d_in[1];
    float* out = (float*)d_out;

    unsigned short* ts_bf = (unsigned short*)d_ws;                 // 2 MB
    unsigned short* nt_bf = ts_bf + NROWS * DDIM;                  // 2 MB
    float* pm = (float*)(nt_bf + NROWS * DDIM);                    // 512 KB
    float* ps = pm + 2 * NROWS * PPART;                            // 512 KB
    float* pd = ps + 2 * NROWS * PPART;                            // 512 KB
    float* acc = pd + 2 * NROWS * PPART;                           // 4 B
    int* ticket = (int*)(acc + 1);                                 // 4 B

    convert_kernel<<<2048, 256, 0, stream>>>(ts, nt, ts_bf, nt_bf, acc, ticket);
    rowstats_kernel<<<dim3(NROWS / BROWS, PPART, 2), 512, 0, stream>>>(ts_bf, nt_bf, pm, ps, pd);
    merge_kernel<<<(2 * NROWS) / 256, 256, 0, stream>>>(pm, ps, pd, acc, ticket, out);
}

// Round 5
// 110.002 us; speedup vs baseline: 2.7242x; 1.0681x over previous
//
#include <hip/hip_runtime.h>
#include <stdint.h>

#define NROWS 8192
#define DDIM  128
#define PPART 8
#define BROWS 256                        // rows per block = 8 waves * 32
#define NITER 16                         // (NROWS/PPART)/64 stages of 64 B-rows
#define LOG2E_X100 144.26950408889634f   // 100 / ln(2)
#define LN2F       0.6931471805599453f

typedef __bf16 bf16x8 __attribute__((ext_vector_type(8)));
typedef float  f32x4  __attribute__((ext_vector_type(4)));

__device__ __forceinline__ unsigned short f2bf_rne(float f) {
    union { float f; uint32_t u; } v; v.f = f;
    uint32_t r = (v.u + 0x7FFFu + ((v.u >> 16) & 1u)) >> 16;
    return (unsigned short)r;
}

// async global->LDS, 16B per lane; lds dest = (uniform base) + lane*16
__device__ __forceinline__ void async16(const unsigned short* g, unsigned char* l) {
    __builtin_amdgcn_global_load_lds(
        (const __attribute__((address_space(1))) unsigned int*)g,
        (__attribute__((address_space(3))) unsigned int*)l, 16, 0, 0);
}

// Kernel 1: fp32 -> bf16. ts pre-scaled by 100*log2(e) (base-2 softmax space).
__global__ void convert_kernel(const float* __restrict__ ts, const float* __restrict__ nt,
                               unsigned short* __restrict__ ts_bf,
                               unsigned short* __restrict__ nt_bf,
                               float* __restrict__ acc, int* __restrict__ ticket) {
    const int nvec = (NROWS * DDIM) / 4;
    int tid = blockIdx.x * blockDim.x + threadIdx.x;
    bool isNT = tid >= nvec;
    int i = isNT ? (tid - nvec) : tid;
    const float4 v = ((const float4*)(isNT ? nt : ts))[i];
    float sc = isNT ? 1.0f : LOG2E_X100;
    ushort4 o;
    o.x = f2bf_rne(v.x * sc); o.y = f2bf_rne(v.y * sc);
    o.z = f2bf_rne(v.z * sc); o.w = f2bf_rne(v.w * sc);
    ((ushort4*)(isNT ? nt_bf : ts_bf))[i] = o;
    if (tid == 0) { *acc = 0.0f; *ticket = 0; }
}

// DMA one 64-row stage (16 KB) into LDS, split across 8 waves (2 KB each).
// xor-swizzle: 16B chunk ch of row r lands at row-local position ch ^ (r&7).
__device__ __forceinline__ void dma_stage(const unsigned short* g, unsigned char* l,
                                          int lane, int wv) {
#pragma unroll
    for (int k = 0; k < 2; ++k) {
        int u = wv * 2 + k;                    // chunk 0..15 (4 rows each)
        int r = u * 4 + (lane >> 4);           // stage row 0..63
        int ch = (lane & 15) ^ (r & 7);        // global 16B chunk this lane fetches
        async16(g + r * 128 + ch * 8, l + u * 1024);
    }
}

// Kernel 2: per-row online-softmax stats, base-2 space.
// 8 waves/block; each wave = 32 rows (2 strips). Stages of 4 j-tiles (64 B-rows)
// staged in double-buffered LDS; DMA balanced across waves; 4-slot batched
// softmax update (1.25 exp2/element). grid = (NROWS/BROWS, PPART, 2).
__global__ __launch_bounds__(512, 4) void rowstats_kernel(
        const unsigned short* __restrict__ ts_bf,
        const unsigned short* __restrict__ nt_bf,
        float* __restrict__ pm, float* __restrict__ ps, float* __restrict__ pd) {
    __shared__ unsigned char smem[2 * 16384];

    const int lane = threadIdx.x & 63;
    const int wv   = threadIdx.x >> 6;         // 0..7
    const int c    = lane & 15;
    const int quad = lane >> 4;
    const int bx   = blockIdx.x;               // 0..31
    const int part = blockIdx.y;               // 0..7
    const int dir  = blockIdx.z;
    const int rows0 = bx * BROWS + wv * 32;

    const unsigned short* A = dir ? nt_bf : ts_bf;
    const unsigned short* B = dir ? ts_bf : nt_bf;

    // A fragments: this wave's 32 rows (2 strips), in regs (32 VGPRs).
    bf16x8 a[2][4];
#pragma unroll
    for (int s = 0; s < 2; ++s) {
        const unsigned short* abase = A + (rows0 + s * 16 + c) * DDIM + quad * 8;
#pragma unroll
        for (int kc = 0; kc < 4; ++kc)
            a[s][kc] = *(const bf16x8*)(abase + kc * 32);
    }

    float m[2][4], ss[2][4], dg[2][4];
#pragma unroll
    for (int s = 0; s < 2; ++s)
#pragma unroll
        for (int r = 0; r < 4; ++r) { m[s][r] = -INFINITY; ss[s][r] = 0.0f; dg[s][r] = 0.0f; }

    // Diagonal bookkeeping. Wave's diag tiles g0=rows0/16 (even) and g0+1 are
    // always inside one 4-tile stage of partition bx>>2.
    const bool havePart = (part == (bx >> 2));
    const int  t_d = (bx & 3) * 4 + (wv >> 1);   // stage containing diag tiles
    const int  l0  = (wv & 1) * 2;               // slot of strip0's diag tile

    const unsigned short* bwalk = B + part * (NROWS / PPART) * DDIM;

    dma_stage(bwalk, smem, lane, wv);
    __syncthreads();

    for (int t = 0; t < NITER; ++t) {
        if (t + 1 < NITER)
            dma_stage(bwalk + (t + 1) * 64 * DDIM, smem + ((t + 1) & 1) * 16384, lane, wv);

        const unsigned char* buf = smem + (t & 1) * 16384;

        f32x4 acc[4][2];
#pragma unroll
        for (int l = 0; l < 4; ++l)
#pragma unroll
            for (int s = 0; s < 2; ++s) acc[l][s] = (f32x4){0.f, 0.f, 0.f, 0.f};

#pragma unroll
        for (int kc = 0; kc < 4; ++kc) {
            const int sw = ((kc * 4 + quad) ^ (c & 7)) * 16;
            const unsigned char* p = buf + c * 256 + sw;
            bf16x8 b0 = *(const bf16x8*)(p);
            bf16x8 b1 = *(const bf16x8*)(p + 4096);
            bf16x8 b2 = *(const bf16x8*)(p + 8192);
            bf16x8 b3 = *(const bf16x8*)(p + 12288);
            acc[0][0] = __builtin_amdgcn_mfma_f32_16x16x32_bf16(a[0][kc], b0, acc[0][0], 0, 0, 0);
            acc[0][1] = __builtin_amdgcn_mfma_f32_16x16x32_bf16(a[1][kc], b0, acc[0][1], 0, 0, 0);
            acc[1][0] = __builtin_amdgcn_mfma_f32_16x16x32_bf16(a[0][kc], b1, acc[1][0], 0, 0, 0);
            acc[1][1] = __builtin_amdgcn_mfma_f32_16x16x32_bf16(a[1][kc], b1, acc[1][1], 0, 0, 0);
            acc[2][0] = __builtin_amdgcn_mfma_f32_16x16x32_bf16(a[0][kc], b2, acc[2][0], 0, 0, 0);
            acc[2][1] = __builtin_amdgcn_mfma_f32_16x16x32_bf16(a[1][kc], b2, acc[2][1], 0, 0, 0);
            acc[3][0] = __builtin_amdgcn_mfma_f32_16x16x32_bf16(a[0][kc], b3, acc[3][0], 0, 0, 0);
            acc[3][1] = __builtin_amdgcn_mfma_f32_16x16x32_bf16(a[1][kc], b3, acc[3][1], 0, 0, 0);
        }

        const bool pd_ = havePart && (t == t_d);   // wave-uniform, true for 1 stage
#pragma unroll
        for (int s = 0; s < 2; ++s) {
#pragma unroll
            for (int r = 0; r < 4; ++r) {
                float x0 = acc[0][s][r], x1 = acc[1][s][r];
                float x2 = acc[2][s][r], x3 = acc[3][s][r];
                if (pd_) {
                    const int dslot = l0 + s;       // wave-uniform 0..3
                    bool onDiag = (c == quad * 4 + r);
                    float xv = dslot == 0 ? x0 : dslot == 1 ? x1 : dslot == 2 ? x2 : x3;
                    if (onDiag) dg[s][r] += xv;
                    float rep = onDiag ? xv : -1.0e30f;
                    if (dslot == 0) x0 = rep; else if (dslot == 1) x1 = rep;
                    else if (dslot == 2) x2 = rep; else x3 = rep;
                }
                float mn = fmaxf(fmaxf(fmaxf(x0, x1), fmaxf(x2, x3)), m[s][r]);
                float e  = __builtin_amdgcn_exp2f(m[s][r] - mn);
                float es = (__builtin_amdgcn_exp2f(x0 - mn) + __builtin_amdgcn_exp2f(x1 - mn))
                         + (__builtin_amdgcn_exp2f(x2 - mn) + __builtin_amdgcn_exp2f(x3 - mn));
                ss[s][r] = fmaf(ss[s][r], e, es);
                m[s][r] = mn;
            }
        }
        __syncthreads();
    }

    // Epilogue: 16-lane combine per quad. Max-reduce, single rescale, sum-reduce.
#pragma unroll
    for (int s = 0; s < 2; ++s) {
#pragma unroll
        for (int r = 0; r < 4; ++r) {
            float mm = m[s][r];
#pragma unroll
            for (int off = 1; off < 16; off <<= 1)
                mm = fmaxf(mm, __shfl_xor(mm, off, 64));
            float sv = ss[s][r] * __builtin_amdgcn_exp2f(m[s][r] - mm);
            float dd = dg[s][r];
#pragma unroll
            for (int off = 1; off < 16; off <<= 1) {
                sv += __shfl_xor(sv, off, 64);
                dd += __shfl_xor(dd, off, 64);
            }
            if (c == 0) {
                int row = rows0 + s * 16 + quad * 4 + r;
                int idx = (dir * NROWS + row) * PPART + part;
                pm[idx] = mm; ps[idx] = sv; pd[idx] = dd;
            }
        }
    }
}

// Kernel 3: merge partitions per (dir,row), block-reduce, atomicAdd;
// last block finalizes the scalar output (base-2 -> natural via ln2).
__global__ void merge_kernel(const float* __restrict__ pm, const float* __restrict__ ps,
                             const float* __restrict__ pd, float* __restrict__ acc,
                             int* __restrict__ ticket, float* __restrict__ out) {
    int tid = blockIdx.x * blockDim.x + threadIdx.x;  // 0 .. 2*NROWS-1
    const float* pmr = pm + tid * PPART;
    const float* psr = ps + tid * PPART;
    const float* pdr = pd + tid * PPART;
    float mt = -INFINITY;
#pragma unroll
    for (int p = 0; p < PPART; ++p) mt = fmaxf(mt, pmr[p]);
    float st = 0.0f, dt = 0.0f;
#pragma unroll
    for (int p = 0; p < PPART; ++p) {
        st += psr[p] * __builtin_amdgcn_exp2f(pmr[p] - mt);
        dt += pdr[p];
    }
    float lsm = dt - mt - __builtin_amdgcn_logf(st);   // base-2 log-softmax at diagonal

    float v = lsm;
#pragma unroll
    for (int off = 32; off; off >>= 1) v += __shfl_down(v, off, 64);
    __shared__ float wsum[4];
    if ((threadIdx.x & 63) == 0) wsum[threadIdx.x >> 6] = v;
    __syncthreads();
    if (threadIdx.x == 0) {
        atomicAdd(acc, wsum[0] + wsum[1] + wsum[2] + wsum[3]);
        __threadfence();
        int old = atomicAdd(ticket, 1);
        if (old == (int)gridDim.x - 1) {
            __threadfence();
            float tot = atomicAdd(acc, 0.0f);   // coherent read of final sum
            float t = -(tot * LN2F) / (2.0f * NROWS);
            if (!isfinite(t)) t = 0.0f;
            out[0] = t;
        }
    }
}

extern "C" void kernel_launch(void* const* d_in, const int* in_sizes, int n_in,
                              void* d_out, int out_size, void* d_ws, size_t ws_size,
                              hipStream_t stream) {
    const float* ts = (const float*)d_in[0];
    const float* nt = (const float*)d_in[1];
    float* out = (float*)d_out;

    unsigned short* ts_bf = (unsigned short*)d_ws;                 // 2 MB
    unsigned short* nt_bf = ts_bf + NROWS * DDIM;                  // 2 MB
    float* pm = (float*)(nt_bf + NROWS * DDIM);                    // 512 KB
    float* ps = pm + 2 * NROWS * PPART;                            // 512 KB
    float* pd = ps + 2 * NROWS * PPART;                            // 512 KB
    float* acc = pd + 2 * NROWS * PPART;                           // 4 B
    int* ticket = (int*)(acc + 1);                                 // 4 B

    convert_kernel<<<2048, 256, 0, stream>>>(ts, nt, ts_bf, nt_bf, acc, ticket);
    rowstats_kernel<<<dim3(NROWS / BROWS, PPART, 2), 512, 0, stream>>>(ts_bf, nt_bf, pm, ps, pd);
    merge_kernel<<<(2 * NROWS) / 256, 256, 0, stream>>>(pm, ps, pd, acc, ticket, out);
}